// Round 2
// baseline (45.701 us; speedup 1.0000x reference)
//
#include <hip/hip_runtime.h>
#include <hip/hip_bf16.h>
#include <hip/hip_fp16.h>

typedef __attribute__((ext_vector_type(8))) short short8;   // 8 x bf16 (4 VGPRs)
typedef __attribute__((ext_vector_type(4))) float f32x4;    // MFMA accumulator

#define OUT_F  11008
#define IN_F   4096
#define BN     64
#define SPLITS 4
#define KSTEPS 8              // 128-wide K steps per split (4*8*128 = 4096)
#define NB     (OUT_F / BN)   // 172

// ---------- helpers ----------
static __device__ __forceinline__ uint pack2_bf16(float a, float b) {
    __hip_bfloat162 h = __float22bfloat162_rn(make_float2(a, b));
    uint u;
    __builtin_memcpy(&u, &h, 4);
    return u;
}

static __device__ __forceinline__ float bf16_to_f(ushort u) {
    return __uint_as_float(((uint)u) << 16);
}

// dequant 4 weights from one packed int (low byte): w = xmin + q * d
static __device__ __forceinline__ uint2 dq4(int p, float xmin, float dd) {
    float w0 = fmaf((float)(p & 3), dd, xmin);
    float w1 = fmaf((float)((p >> 2) & 3), dd, xmin);
    float w2 = fmaf((float)((p >> 4) & 3), dd, xmin);
    float w3 = fmaf((float)((p >> 6) & 3), dd, xmin);
    return make_uint2(pack2_bf16(w0, w1), pack2_bf16(w2, w3));
}

// decode group g's (xmin, dd) under detected format
static __device__ __forceinline__ void range_decode(const void* rr, int g, int fmt,
                                                    float& xmin, float& dd) {
    float xmax;
    if (fmt == 2) {
        const float2 f = ((const float2*)rr)[g];
        xmin = f.x; xmax = f.y;
    } else if (fmt == 1) {
        const ushort2 u = ((const ushort2*)rr)[g];
        xmin = bf16_to_f(u.x); xmax = bf16_to_f(u.y);
    } else {
        const __half2 h = ((const __half2*)rr)[g];
        xmin = __half2float(h.x); xmax = __half2float(h.y);
    }
    dd = (xmax - xmin) * (1.0f / 3.0f);
}

// ---------- kernel 1: x(f32)->bf16 into ws, out = bias, + range-format detect ----------
__global__ __launch_bounds__(256)
void prep_kernel(const float* __restrict__ x,
                 const float* __restrict__ bias,
                 const void* __restrict__ rr,
                 float* __restrict__ out,
                 ushort* __restrict__ xb,
                 int* __restrict__ fmt_flag) {
    const int b = blockIdx.x;
    const int t = threadIdx.x;
    if (b < 128) {
        // 32*4096 floats; 4/thread; 128*256*4 = 131072
        const int i = b * 256 + t;
        const float4 v = ((const float4*)x)[i];
        ushort4 o;
        __hip_bfloat16 h0 = __float2bfloat16(v.x);
        __hip_bfloat16 h1 = __float2bfloat16(v.y);
        __hip_bfloat16 h2 = __float2bfloat16(v.z);
        __hip_bfloat16 h3 = __float2bfloat16(v.w);
        __builtin_memcpy(&o.x, &h0, 2);
        __builtin_memcpy(&o.y, &h1, 2);
        __builtin_memcpy(&o.z, &h2, 2);
        __builtin_memcpy(&o.w, &h3, 2);
        ((ushort4*)xb)[i] = o;
    } else if (b < 472) {
        // out[m][n] = bias[n]; 344*256 float4 = 88064 = 32*11008/4
        const int i = (b - 128) * 256 + t;
        const int m = i / 2752;       // 11008/4 = 2752
        const int n4 = i % 2752;
        ((float4*)out)[m * 2752 + n4] = ((const float4*)bias)[n4];
    } else {
        // --- range dtype detection over 1024 sampled groups ---
        // reads bounded to g < 176128 so even the smallest (16-bit) actual
        // buffer (704512*2 bytes) is never exceeded under the f32 hypothesis.
        __shared__ int s_viol[3];
        __shared__ int s_max[3];
        if (t < 3) { s_viol[t] = 0; s_max[t] = 0; }
        __syncthreads();
        int viol[3] = {0, 0, 0};
        float mx[3] = {0.f, 0.f, 0.f};
        for (int j = 0; j < 4; ++j) {
            const int g = t * 686 + j * 171 + 1;   // max 175445 < 176128
            {   // hypothesis 0: fp16 pairs
                const __half2 h = ((const __half2*)rr)[g];
                const float a = __half2float(h.x), c = __half2float(h.y);
                if (!(fabsf(a) < 1.f && fabsf(c) < 1.f && a <= c)) viol[0] = 1;
                mx[0] = fmaxf(mx[0], fabsf(c));
            }
            {   // hypothesis 1: bf16 pairs
                const ushort2 u = ((const ushort2*)rr)[g];
                const float a = bf16_to_f(u.x), c = bf16_to_f(u.y);
                if (!(fabsf(a) < 1.f && fabsf(c) < 1.f && a <= c)) viol[1] = 1;
                mx[1] = fmaxf(mx[1], fabsf(c));
            }
            {   // hypothesis 2: f32 pairs
                const float2 f = ((const float2*)rr)[g];
                if (!(fabsf(f.x) < 1.f && fabsf(f.y) < 1.f && f.x <= f.y)) viol[2] = 1;
                mx[2] = fmaxf(mx[2], fabsf(f.y));
            }
        }
#pragma unroll
        for (int h = 0; h < 3; ++h) {
            if (viol[h]) atomicOr(&s_viol[h], 1);
            atomicMax(&s_max[h], __float_as_int(mx[h]));
        }
        __syncthreads();
        if (t == 0) {
            const float lo = 0.02f;
            int f = 0;
            if      (!s_viol[2] && __int_as_float(s_max[2]) > lo) f = 2;
            else if (!s_viol[1] && __int_as_float(s_max[1]) > lo) f = 1;
            *fmt_flag = f;
        }
    }
}

// ---------- kernel 2: fused dequant + GEMM ----------
__global__ __launch_bounds__(256, 4)
void gemm_kernel(const int* __restrict__ packed,
                 const void* __restrict__ rr,
                 const ushort* __restrict__ xb,
                 const int* __restrict__ fmtp,
                 float* __restrict__ out) {
    const int nb   = blockIdx.x;   // 0..171  (64 output cols each)
    const int s    = blockIdx.y;   // 0..3    (K split: 1024 each)
    const int t    = threadIdx.x;  // 0..255
    const int lane = t & 63;
    const int wv   = t >> 6;       // wave id 0..3 -> 16 cols each
    const int fmt  = *fmtp;        // uniform

    // W tile: 64 rows x 128 bf16, XOR-swizzled to kill ds_read_b128 conflicts
    __shared__ __align__(16) char wtile[BN * 256];  // 16 KiB

    const int i4  = t & 7;   // which int4 within the group's 32 ints
    const int nr0 = t >> 3;  // 0..31 -> rows {nr0, nr0+32}

    f32x4 acc0 = {0.f, 0.f, 0.f, 0.f};
    f32x4 acc1 = {0.f, 0.f, 0.f, 0.f};

    // A fragment base: row (lane&15), k offset (lane>>4)*8 (bf16, row-major [32][4096])
    const ushort* xa = xb + (lane & 15) * IN_F + ((lane >> 4) << 3);

    for (int step = 0; step < KSTEPS; ++step) {
        const int kb = s * KSTEPS + step;  // global 128-group index along K, 0..31
        const int k0 = kb << 7;

        // --- A fragments straight from global (x is tiny: L1/L2 resident) ---
        short8 a0[4], a1[4];
#pragma unroll
        for (int kc = 0; kc < 4; ++kc) {
            a0[kc] = *(const short8*)(xa + k0 + kc * 32);
            a1[kc] = *(const short8*)(xa + 16 * IN_F + k0 + kc * 32);
        }

        // --- stage dequantized W tile into LDS ---
#pragma unroll
        for (int h = 0; h < 2; ++h) {
            const int nr = nr0 + h * 32;
            const int n  = nb * BN + nr;
            // packed flat: n*1024 + kb*32 + int_idx
            const int4 p4 = *(const int4*)(packed + n * 1024 + kb * 32 + i4 * 4);
            float xmin, dd;
            range_decode(rr, n * 32 + kb, fmt, xmin, dd);
            char* dst = wtile + nr * 256;
            const uint swz = (uint)((nr & 7) << 4);
            uint2 q0 = dq4(p4.x, xmin, dd);
            uint2 q1 = dq4(p4.y, xmin, dd);
            *(uint4*)(dst + (uint)((32 * i4) ^ swz)) = make_uint4(q0.x, q0.y, q1.x, q1.y);
            uint2 q2 = dq4(p4.z, xmin, dd);
            uint2 q3 = dq4(p4.w, xmin, dd);
            *(uint4*)(dst + (uint)((32 * i4 + 16) ^ swz)) = make_uint4(q2.x, q2.y, q3.x, q3.y);
        }
        __syncthreads();

        // --- B fragments from swizzled LDS + MFMA ---
        const int  nrow = (wv << 4) | (lane & 15);
        const char* src = wtile + nrow * 256;
        const uint swzr = (uint)((nrow & 7) << 4);
#pragma unroll
        for (int kc = 0; kc < 4; ++kc) {
            short8 bf = *(const short8*)(src + (uint)((((kc << 6) | ((lane >> 4) << 4))) ^ swzr));
            acc0 = __builtin_amdgcn_mfma_f32_16x16x32_bf16(a0[kc], bf, acc0, 0, 0, 0);
            acc1 = __builtin_amdgcn_mfma_f32_16x16x32_bf16(a1[kc], bf, acc1, 0, 0, 0);
        }
        __syncthreads();
    }

    // --- epilogue: C/D layout col=lane&15, row=(lane>>4)*4+reg (m89-verified) ---
    const int col = nb * BN + (wv << 4) + (lane & 15);
    const int r0  = (lane >> 4) << 2;
#pragma unroll
    for (int v = 0; v < 4; ++v) {
        atomicAdd(out + (r0 + v) * OUT_F + col,        acc0[v]);
        atomicAdd(out + (16 + r0 + v) * OUT_F + col,   acc1[v]);
    }
}

extern "C" void kernel_launch(void* const* d_in, const int* in_sizes, int n_in,
                              void* d_out, int out_size, void* d_ws, size_t ws_size,
                              hipStream_t stream) {
    const float* x      = (const float*)d_in[0];
    const int*   packed = (const int*)d_in[1];
    const void*  rr     = (const void*)d_in[2];
    const float* bias   = (const float*)d_in[3];
    float*       out    = (float*)d_out;

    int*    fmt_flag = (int*)d_ws;
    ushort* xb       = (ushort*)((char*)d_ws + 256);   // 32*4096 bf16 = 256 KiB

    prep_kernel<<<473, 256, 0, stream>>>(x, bias, rr, out, xb, fmt_flag);
    gemm_kernel<<<dim3(NB, SPLITS), 256, 0, stream>>>(packed, rr, xb, fmt_flag, out);
}

// Round 3
// 44.199 us; speedup vs baseline: 1.0340x; 1.0340x over previous
//
#include <hip/hip_runtime.h>
#include <hip/hip_bf16.h>
#include <hip/hip_fp16.h>

typedef __attribute__((ext_vector_type(8))) short short8;   // 8 x bf16 (4 VGPRs)
typedef __attribute__((ext_vector_type(4))) float f32x4;    // MFMA accumulator

#define OUT_F  11008
#define IN_F   4096
#define BN     64
#define SPLITS 4
#define KSTEPS 8              // 128-wide K steps per split (4*8*128 = 4096)
#define NB     (OUT_F / BN)   // 172

// ---------- helpers ----------
static __device__ __forceinline__ uint pack2_bf16(float a, float b) {
    __hip_bfloat162 h = __float22bfloat162_rn(make_float2(a, b));
    uint u;
    __builtin_memcpy(&u, &h, 4);
    return u;
}

static __device__ __forceinline__ float bf16_to_f(ushort u) {
    return __uint_as_float(((uint)u) << 16);
}

// dequant 4 weights from one packed int (low byte): w = xmin + q * d
static __device__ __forceinline__ uint2 dq4(int p, float xmin, float dd) {
    float w0 = fmaf((float)(p & 3), dd, xmin);
    float w1 = fmaf((float)((p >> 2) & 3), dd, xmin);
    float w2 = fmaf((float)((p >> 4) & 3), dd, xmin);
    float w3 = fmaf((float)((p >> 6) & 3), dd, xmin);
    return make_uint2(pack2_bf16(w0, w1), pack2_bf16(w2, w3));
}

// decode a prefetched raw range pair under detected format
static __device__ __forceinline__ void rng_decode(uint ru, float2 rf, int fmt,
                                                  float& xmin, float& dd) {
    float xmax;
    if (fmt == 2) {
        xmin = rf.x; xmax = rf.y;
    } else if (fmt == 1) {
        xmin = bf16_to_f((ushort)(ru & 0xffff));
        xmax = bf16_to_f((ushort)(ru >> 16));
    } else {
        __half2 h;
        __builtin_memcpy(&h, &ru, 4);
        xmin = __half2float(h.x); xmax = __half2float(h.y);
    }
    dd = (xmax - xmin) * (1.0f / 3.0f);
}

// ---------- kernel 1: x(f32)->bf16 into ws, out = bias, + range-format detect ----------
__global__ __launch_bounds__(256)
void prep_kernel(const float* __restrict__ x,
                 const float* __restrict__ bias,
                 const void* __restrict__ rr,
                 float* __restrict__ out,
                 ushort* __restrict__ xb,
                 int* __restrict__ fmt_flag) {
    const int b = blockIdx.x;
    const int t = threadIdx.x;
    if (b < 128) {
        // 32*4096 floats; 4/thread; 128*256*4 = 131072
        const int i = b * 256 + t;
        const float4 v = ((const float4*)x)[i];
        ushort4 o;
        __hip_bfloat16 h0 = __float2bfloat16(v.x);
        __hip_bfloat16 h1 = __float2bfloat16(v.y);
        __hip_bfloat16 h2 = __float2bfloat16(v.z);
        __hip_bfloat16 h3 = __float2bfloat16(v.w);
        __builtin_memcpy(&o.x, &h0, 2);
        __builtin_memcpy(&o.y, &h1, 2);
        __builtin_memcpy(&o.z, &h2, 2);
        __builtin_memcpy(&o.w, &h3, 2);
        ((ushort4*)xb)[i] = o;
    } else if (b < 472) {
        // out[m][n] = bias[n]; 344*256 float4 = 88064 = 32*11008/4
        const int i = (b - 128) * 256 + t;
        const int m = i / 2752;       // 11008/4 = 2752
        const int n4 = i % 2752;
        ((float4*)out)[m * 2752 + n4] = ((const float4*)bias)[n4];
    } else {
        // --- range dtype detection, COALESCED: 4 rounds of 256 consecutive groups ---
        // max g = 1024 + 3*40000 + 255 = 121279 < 176128, so even the smallest
        // possible (16-bit) actual buffer is never exceeded under the f32 read.
        __shared__ int s_viol[3];
        __shared__ int s_max[3];
        if (t < 3) { s_viol[t] = 0; s_max[t] = 0; }
        __syncthreads();
        int viol[3] = {0, 0, 0};
        float mx[3] = {0.f, 0.f, 0.f};
        for (int j = 0; j < 4; ++j) {
            const int g = 1024 + j * 40000 + t;   // contiguous within each round
            {   // hypothesis 0: fp16 pairs
                const __half2 h = ((const __half2*)rr)[g];
                const float a = __half2float(h.x), c = __half2float(h.y);
                if (!(fabsf(a) < 1.f && fabsf(c) < 1.f && a <= c)) viol[0] = 1;
                mx[0] = fmaxf(mx[0], fabsf(c));
            }
            {   // hypothesis 1: bf16 pairs
                const ushort2 u = ((const ushort2*)rr)[g];
                const float a = bf16_to_f(u.x), c = bf16_to_f(u.y);
                if (!(fabsf(a) < 1.f && fabsf(c) < 1.f && a <= c)) viol[1] = 1;
                mx[1] = fmaxf(mx[1], fabsf(c));
            }
            {   // hypothesis 2: f32 pairs
                const float2 f = ((const float2*)rr)[g];
                if (!(fabsf(f.x) < 1.f && fabsf(f.y) < 1.f && f.x <= f.y)) viol[2] = 1;
                mx[2] = fmaxf(mx[2], fabsf(f.y));
            }
        }
#pragma unroll
        for (int h = 0; h < 3; ++h) {
            if (viol[h]) atomicOr(&s_viol[h], 1);
            atomicMax(&s_max[h], __float_as_int(mx[h]));
        }
        __syncthreads();
        if (t == 0) {
            const float lo = 0.02f;
            int f = 0;
            if      (!s_viol[2] && __int_as_float(s_max[2]) > lo) f = 2;
            else if (!s_viol[1] && __int_as_float(s_max[1]) > lo) f = 1;
            *fmt_flag = f;
        }
    }
}

// ---------- kernel 2: fused dequant + GEMM, 1-deep global->reg prefetch ----------
__global__ __launch_bounds__(256, 3)
void gemm_kernel(const int* __restrict__ packed,
                 const void* __restrict__ rr,
                 const ushort* __restrict__ xb,
                 const int* __restrict__ fmtp,
                 float* __restrict__ out) {
    const int nb   = blockIdx.x;   // 0..171  (64 output cols each)
    const int s    = blockIdx.y;   // 0..3    (K split: 1024 each)
    const int t    = threadIdx.x;  // 0..255
    const int lane = t & 63;
    const int wv   = t >> 6;       // wave id 0..3 -> 16 cols each
    const int fmt  = *fmtp;        // uniform

    // W tile: 64 rows x 128 bf16, XOR-swizzled to kill ds_read_b128 conflicts
    __shared__ __align__(16) char wtile[BN * 256];  // 16 KiB

    const int i4  = t & 7;   // which int4 within the group's 32 ints
    const int nr0 = t >> 3;  // 0..31 -> rows {nr0, nr0+32}

    f32x4 acc0 = {0.f, 0.f, 0.f, 0.f};
    f32x4 acc1 = {0.f, 0.f, 0.f, 0.f};

    // A fragment base: row (lane&15), k offset (lane>>4)*8 (bf16, row-major [32][4096])
    const ushort* xa = xb + (lane & 15) * IN_F + ((lane >> 4) << 3);

    // per-thread source bases for the two staged rows
    const int n0 = nb * BN + nr0;          // row 0..31 of tile
    const int n1 = n0 + 32;                // row 32..63
    const int kb0 = s * KSTEPS;
    const int* pbase0 = packed + n0 * 1024 + i4 * 4;
    const int* pbase1 = packed + n1 * 1024 + i4 * 4;

    // ---- prologue: load step 0 operands into registers ----
    int4  p4c0 = *(const int4*)(pbase0 + kb0 * 32);
    int4  p4c1 = *(const int4*)(pbase1 + kb0 * 32);
    uint  ruc0 = 0, ruc1 = 0;
    float2 rfc0 = {0.f, 0.f}, rfc1 = {0.f, 0.f};
    if (fmt == 2) {
        rfc0 = ((const float2*)rr)[n0 * 32 + kb0];
        rfc1 = ((const float2*)rr)[n1 * 32 + kb0];
    } else {
        ruc0 = ((const uint*)rr)[n0 * 32 + kb0];
        ruc1 = ((const uint*)rr)[n1 * 32 + kb0];
    }

    for (int step = 0; step < KSTEPS; ++step) {
        const int kb = kb0 + step;
        const int k0 = kb << 7;

        // --- A fragments straight from global (x is tiny: L1/L2 resident) ---
        short8 a0[4], a1[4];
#pragma unroll
        for (int kc = 0; kc < 4; ++kc) {
            a0[kc] = *(const short8*)(xa + k0 + kc * 32);
            a1[kc] = *(const short8*)(xa + 16 * IN_F + k0 + kc * 32);
        }

        __syncthreads();   // all waves done reading previous LDS tile

        // --- issue NEXT step's global loads first (latency hides under
        //     dequant+MFMA of the current step) ---
        int4 p4n0, p4n1;
        uint run0 = 0, run1 = 0;
        float2 rfn0, rfn1;
        if (step + 1 < KSTEPS) {
            const int kn = kb + 1;
            p4n0 = *(const int4*)(pbase0 + kn * 32);
            p4n1 = *(const int4*)(pbase1 + kn * 32);
            if (fmt == 2) {
                rfn0 = ((const float2*)rr)[n0 * 32 + kn];
                rfn1 = ((const float2*)rr)[n1 * 32 + kn];
            } else {
                run0 = ((const uint*)rr)[n0 * 32 + kn];
                run1 = ((const uint*)rr)[n1 * 32 + kn];
            }
        }

        // --- dequant current registers -> swizzled LDS ---
        {
            float xmin, dd;
            rng_decode(ruc0, rfc0, fmt, xmin, dd);
            char* dst = wtile + nr0 * 256;
            const uint swz = (uint)((nr0 & 7) << 4);
            uint2 q0 = dq4(p4c0.x, xmin, dd);
            uint2 q1 = dq4(p4c0.y, xmin, dd);
            *(uint4*)(dst + (uint)((32 * i4) ^ swz)) = make_uint4(q0.x, q0.y, q1.x, q1.y);
            uint2 q2 = dq4(p4c0.z, xmin, dd);
            uint2 q3 = dq4(p4c0.w, xmin, dd);
            *(uint4*)(dst + (uint)((32 * i4 + 16) ^ swz)) = make_uint4(q2.x, q2.y, q3.x, q3.y);
        }
        {
            float xmin, dd;
            rng_decode(ruc1, rfc1, fmt, xmin, dd);
            const int nr = nr0 + 32;
            char* dst = wtile + nr * 256;
            const uint swz = (uint)((nr & 7) << 4);
            uint2 q0 = dq4(p4c1.x, xmin, dd);
            uint2 q1 = dq4(p4c1.y, xmin, dd);
            *(uint4*)(dst + (uint)((32 * i4) ^ swz)) = make_uint4(q0.x, q0.y, q1.x, q1.y);
            uint2 q2 = dq4(p4c1.z, xmin, dd);
            uint2 q3 = dq4(p4c1.w, xmin, dd);
            *(uint4*)(dst + (uint)((32 * i4 + 16) ^ swz)) = make_uint4(q2.x, q2.y, q3.x, q3.y);
        }
        __syncthreads();

        // --- B fragments from swizzled LDS + MFMA ---
        const int  nrow = (wv << 4) | (lane & 15);
        const char* src = wtile + nrow * 256;
        const uint swzr = (uint)((nrow & 7) << 4);
#pragma unroll
        for (int kc = 0; kc < 4; ++kc) {
            short8 bf = *(const short8*)(src + (uint)((((kc << 6) | ((lane >> 4) << 4))) ^ swzr));
            acc0 = __builtin_amdgcn_mfma_f32_16x16x32_bf16(a0[kc], bf, acc0, 0, 0, 0);
            acc1 = __builtin_amdgcn_mfma_f32_16x16x32_bf16(a1[kc], bf, acc1, 0, 0, 0);
        }

        // rotate prefetched registers into current slot
        if (step + 1 < KSTEPS) {
            p4c0 = p4n0; p4c1 = p4n1;
            ruc0 = run0; ruc1 = run1;
            rfc0 = rfn0; rfc1 = rfn1;
        }
    }

    // --- epilogue: C/D layout col=lane&15, row=(lane>>4)*4+reg (m89-verified) ---
    const int col = nb * BN + (wv << 4) + (lane & 15);
    const int r0  = (lane >> 4) << 2;
#pragma unroll
    for (int v = 0; v < 4; ++v) {
        atomicAdd(out + (r0 + v) * OUT_F + col,        acc0[v]);
        atomicAdd(out + (16 + r0 + v) * OUT_F + col,   acc1[v]);
    }
}

extern "C" void kernel_launch(void* const* d_in, const int* in_sizes, int n_in,
                              void* d_out, int out_size, void* d_ws, size_t ws_size,
                              hipStream_t stream) {
    const float* x      = (const float*)d_in[0];
    const int*   packed = (const int*)d_in[1];
    const void*  rr     = (const void*)d_in[2];
    const float* bias   = (const float*)d_in[3];
    float*       out    = (float*)d_out;

    int*    fmt_flag = (int*)d_ws;
    ushort* xb       = (ushort*)((char*)d_ws + 256);   // 32*4096 bf16 = 256 KiB

    prep_kernel<<<473, 256, 0, stream>>>(x, bias, rr, out, xb, fmt_flag);
    gemm_kernel<<<dim3(NB, SPLITS), 256, 0, stream>>>(packed, rr, xb, fmt_flag, out);
}

// Round 4
// 35.587 us; speedup vs baseline: 1.2842x; 1.2420x over previous
//
#include <hip/hip_runtime.h>
#include <hip/hip_bf16.h>
#include <hip/hip_fp16.h>

typedef __attribute__((ext_vector_type(8))) short short8;   // 8 x bf16 (4 VGPRs)
typedef __attribute__((ext_vector_type(4))) float f32x4;    // MFMA accumulator

#define OUT_F  11008
#define IN_F   4096
#define BN     64
#define SPLITS 4
#define KSTEPS 8              // 128-wide K steps per split (4*8*128 = 4096)
#define NB     (OUT_F / BN)   // 172

// ---------- helpers ----------
static __device__ __forceinline__ uint pack2_bf16(float a, float b) {
    __hip_bfloat162 h = __float22bfloat162_rn(make_float2(a, b));
    uint u;
    __builtin_memcpy(&u, &h, 4);
    return u;
}

static __device__ __forceinline__ float bf16_to_f(ushort u) {
    return __uint_as_float(((uint)u) << 16);
}

// dequant 4 weights from one packed int (low byte): w = xmin + q * d
static __device__ __forceinline__ uint2 dq4(int p, float xmin, float dd) {
    float w0 = fmaf((float)(p & 3), dd, xmin);
    float w1 = fmaf((float)((p >> 2) & 3), dd, xmin);
    float w2 = fmaf((float)((p >> 4) & 3), dd, xmin);
    float w3 = fmaf((float)((p >> 6) & 3), dd, xmin);
    return make_uint2(pack2_bf16(w0, w1), pack2_bf16(w2, w3));
}

// decode a prefetched raw range pair under detected format
static __device__ __forceinline__ void rng_decode(uint ru, float2 rf, int fmt,
                                                  float& xmin, float& dd) {
    float xmax;
    if (fmt == 2) {
        xmin = rf.x; xmax = rf.y;
    } else if (fmt == 1) {
        xmin = bf16_to_f((ushort)(ru & 0xffff));
        xmax = bf16_to_f((ushort)(ru >> 16));
    } else {
        __half2 h;
        __builtin_memcpy(&h, &ru, 4);
        xmin = __half2float(h.x); xmax = __half2float(h.y);
    }
    dd = (xmax - xmin) * (1.0f / 3.0f);
}

// ---------- kernel 1: out = bias broadcast (tiny) ----------
__global__ __launch_bounds__(256)
void prep_kernel(const float* __restrict__ bias, float* __restrict__ out) {
    // 32*11008/4 = 88064 float4 = 344 blocks * 256 threads
    const int i = blockIdx.x * 256 + threadIdx.x;
    const int m  = i / 2752;        // 11008/4 = 2752
    const int n4 = i % 2752;
    ((float4*)out)[m * 2752 + n4] = ((const float4*)bias)[n4];
}

// ---------- kernel 2: fused detect + dequant + GEMM (NO workspace) ----------
__global__ __launch_bounds__(256, 3)
void gemm_kernel(const float* __restrict__ x,
                 const int* __restrict__ packed,
                 const void* __restrict__ rr,
                 float* __restrict__ out) {
    const int nb   = blockIdx.x;   // 0..171  (64 output cols each)
    const int s    = blockIdx.y;   // 0..3    (K split: 1024 each)
    const int t    = threadIdx.x;  // 0..255
    const int lane = t & 63;
    const int wv   = t >> 6;       // wave id 0..3 -> 16 cols each

    __shared__ __align__(16) char wtile[BN * 256];  // 64 rows x 128 bf16, swizzled (16 KiB)
    __shared__ __align__(16) char atile[32 * 256];  // 32 rows x 128 bf16, swizzled (8 KiB)
    __shared__ int s_viol[3];
    __shared__ int s_max[3];
    __shared__ int s_fmt;

    // ---- block-local range-dtype detection: 256 contiguous front samples ----
    // g in [1024,1280): f32-view reads bytes [8192,10240) -- in-bounds for every
    // possible actual dtype (smallest buffer = 16-bit pairs = 1.4 MB).
    if (t < 3) { s_viol[t] = 0; s_max[t] = 0; }
    __syncthreads();
    {
        const int g = 1024 + t;
        const uint   ru = ((const uint*)rr)[g];
        const float2 rf = ((const float2*)rr)[g];
        int viol[3]; float mx[3];
        {   // h0: fp16 pairs
            __half2 h; __builtin_memcpy(&h, &ru, 4);
            const float a = __half2float(h.x), c = __half2float(h.y);
            viol[0] = !(fabsf(a) < 1.f && fabsf(c) < 1.f && a <= c);
            mx[0] = fabsf(c);
        }
        {   // h1: bf16 pairs
            const float a = bf16_to_f((ushort)(ru & 0xffff));
            const float c = bf16_to_f((ushort)(ru >> 16));
            viol[1] = !(fabsf(a) < 1.f && fabsf(c) < 1.f && a <= c);
            mx[1] = fabsf(c);
        }
        {   // h2: f32 pairs
            viol[2] = !(fabsf(rf.x) < 1.f && fabsf(rf.y) < 1.f && rf.x <= rf.y);
            mx[2] = fabsf(rf.y);
        }
#pragma unroll
        for (int h = 0; h < 3; ++h) {
            if (viol[h]) atomicOr(&s_viol[h], 1);
            atomicMax(&s_max[h], __float_as_int(mx[h]));   // mx >= 0: int-monotone
        }
    }
    __syncthreads();
    if (t == 0) {
        const float lo = 0.02f;
        int f = 0;
        if      (!s_viol[2] && __int_as_float(s_max[2]) > lo) f = 2;
        else if (!s_viol[1] && __int_as_float(s_max[1]) > lo) f = 1;
        s_fmt = f;
    }
    __syncthreads();
    const int fmt = s_fmt;   // uniform

    // ---- addressing ----
    const int i4  = t & 7;   // which int4 within the group's 32 ints
    const int nr0 = t >> 3;  // 0..31 -> W rows {nr0, nr0+32}
    const int n0  = nb * BN + nr0;
    const int n1  = n0 + 32;
    const int kb0 = s * KSTEPS;
    const int* pb0 = packed + n0 * 1024 + i4 * 4;
    const int* pb1 = packed + n1 * 1024 + i4 * 4;

    // x stage (writer): thread covers x row t>>3, 16 floats at col (t&7)*16
    const float* xsrc = x + (t >> 3) * IN_F + (t & 7) * 16;
    char* adst = atile + (t >> 3) * 256;
    const uint aswz = (uint)(((t >> 3) & 7) << 4);

    // A-frag reads: rows lane&15 and (lane&15)+16; same swizzle (row&7 invariant)
    const char* asrc0 = atile + (lane & 15) * 256;
    const char* asrc1 = atile + ((lane & 15) + 16) * 256;
    const uint  arsw  = (uint)((lane & 7) << 4);

    f32x4 acc0 = {0.f, 0.f, 0.f, 0.f};
    f32x4 acc1 = {0.f, 0.f, 0.f, 0.f};

    // ---- prologue: step-0 packed + ranges into registers ----
    int4  p4c0 = *(const int4*)(pb0 + kb0 * 32);
    int4  p4c1 = *(const int4*)(pb1 + kb0 * 32);
    uint  ruc0 = 0, ruc1 = 0;
    float2 rfc0 = {0.f, 0.f}, rfc1 = {0.f, 0.f};
    if (fmt == 2) {
        rfc0 = ((const float2*)rr)[n0 * 32 + kb0];
        rfc1 = ((const float2*)rr)[n1 * 32 + kb0];
    } else {
        ruc0 = ((const uint*)rr)[n0 * 32 + kb0];
        ruc1 = ((const uint*)rr)[n1 * 32 + kb0];
    }

    for (int step = 0; step < KSTEPS; ++step) {
        const int kb = kb0 + step;
        const int k0 = kb << 7;

        // issue this step's x-slice loads (global f32, L2-hot) before the barrier
        float4 xf0 = *(const float4*)(xsrc + k0);
        float4 xf1 = *(const float4*)(xsrc + k0 + 4);
        float4 xf2 = *(const float4*)(xsrc + k0 + 8);
        float4 xf3 = *(const float4*)(xsrc + k0 + 12);

        __syncthreads();   // everyone done reading previous LDS tiles

        // prefetch NEXT step's packed + ranges (latency hides under dequant+MFMA)
        int4 p4n0, p4n1;
        uint run0 = 0, run1 = 0;
        float2 rfn0, rfn1;
        if (step + 1 < KSTEPS) {
            const int kn = kb + 1;
            p4n0 = *(const int4*)(pb0 + kn * 32);
            p4n1 = *(const int4*)(pb1 + kn * 32);
            if (fmt == 2) {
                rfn0 = ((const float2*)rr)[n0 * 32 + kn];
                rfn1 = ((const float2*)rr)[n1 * 32 + kn];
            } else {
                run0 = ((const uint*)rr)[n0 * 32 + kn];
                run1 = ((const uint*)rr)[n1 * 32 + kn];
            }
        }

        // ---- stage x slice -> atile (bf16, swizzled) ----
        {
            uint q0 = pack2_bf16(xf0.x, xf0.y), q1 = pack2_bf16(xf0.z, xf0.w);
            uint q2 = pack2_bf16(xf1.x, xf1.y), q3 = pack2_bf16(xf1.z, xf1.w);
            uint q4 = pack2_bf16(xf2.x, xf2.y), q5 = pack2_bf16(xf2.z, xf2.w);
            uint q6 = pack2_bf16(xf3.x, xf3.y), q7 = pack2_bf16(xf3.z, xf3.w);
            const uint cb = (uint)((t & 7) * 32);
            *(uint4*)(adst + (cb ^ aswz))        = make_uint4(q0, q1, q2, q3);
            *(uint4*)(adst + ((cb + 16) ^ aswz)) = make_uint4(q4, q5, q6, q7);
        }

        // ---- dequant current W registers -> wtile (bf16, swizzled) ----
        {
            float xmin, dd;
            rng_decode(ruc0, rfc0, fmt, xmin, dd);
            char* dst = wtile + nr0 * 256;
            const uint swz = (uint)((nr0 & 7) << 4);
            uint2 q0 = dq4(p4c0.x, xmin, dd);
            uint2 q1 = dq4(p4c0.y, xmin, dd);
            *(uint4*)(dst + (uint)((32 * i4) ^ swz)) = make_uint4(q0.x, q0.y, q1.x, q1.y);
            uint2 q2 = dq4(p4c0.z, xmin, dd);
            uint2 q3 = dq4(p4c0.w, xmin, dd);
            *(uint4*)(dst + (uint)((32 * i4 + 16) ^ swz)) = make_uint4(q2.x, q2.y, q3.x, q3.y);
        }
        {
            float xmin, dd;
            rng_decode(ruc1, rfc1, fmt, xmin, dd);
            const int nr = nr0 + 32;
            char* dst = wtile + nr * 256;
            const uint swz = (uint)((nr & 7) << 4);
            uint2 q0 = dq4(p4c1.x, xmin, dd);
            uint2 q1 = dq4(p4c1.y, xmin, dd);
            *(uint4*)(dst + (uint)((32 * i4) ^ swz)) = make_uint4(q0.x, q0.y, q1.x, q1.y);
            uint2 q2 = dq4(p4c1.z, xmin, dd);
            uint2 q3 = dq4(p4c1.w, xmin, dd);
            *(uint4*)(dst + (uint)((32 * i4 + 16) ^ swz)) = make_uint4(q2.x, q2.y, q3.x, q3.y);
        }
        __syncthreads();

        // ---- A/B fragments from swizzled LDS + MFMA ----
        const int  nrow = (wv << 4) | (lane & 15);
        const char* bsrc = wtile + nrow * 256;
        const uint bswz = (uint)((nrow & 7) << 4);
#pragma unroll
        for (int kc = 0; kc < 4; ++kc) {
            const uint cb = (uint)((kc << 6) | ((lane >> 4) << 4));
            short8 av0 = *(const short8*)(asrc0 + (cb ^ arsw));
            short8 av1 = *(const short8*)(asrc1 + (cb ^ arsw));
            short8 bf  = *(const short8*)(bsrc  + (cb ^ bswz));
            acc0 = __builtin_amdgcn_mfma_f32_16x16x32_bf16(av0, bf, acc0, 0, 0, 0);
            acc1 = __builtin_amdgcn_mfma_f32_16x16x32_bf16(av1, bf, acc1, 0, 0, 0);
        }

        // rotate prefetched registers into current slot
        if (step + 1 < KSTEPS) {
            p4c0 = p4n0; p4c1 = p4n1;
            ruc0 = run0; ruc1 = run1;
            rfc0 = rfn0; rfc1 = rfn1;
        }
    }

    // ---- epilogue: C/D layout col=lane&15, row=(lane>>4)*4+reg (m89-verified) ----
    const int col = nb * BN + (wv << 4) + (lane & 15);
    const int r0  = (lane >> 4) << 2;
#pragma unroll
    for (int v = 0; v < 4; ++v) {
        atomicAdd(out + (r0 + v) * OUT_F + col,        acc0[v]);
        atomicAdd(out + (16 + r0 + v) * OUT_F + col,   acc1[v]);
    }
}

extern "C" void kernel_launch(void* const* d_in, const int* in_sizes, int n_in,
                              void* d_out, int out_size, void* d_ws, size_t ws_size,
                              hipStream_t stream) {
    const float* x      = (const float*)d_in[0];
    const int*   packed = (const int*)d_in[1];
    const void*  rr     = (const void*)d_in[2];
    const float* bias   = (const float*)d_in[3];
    float*       out    = (float*)d_out;
    (void)d_ws; (void)ws_size;   // workspace deliberately unused

    prep_kernel<<<344, 256, 0, stream>>>(bias, out);
    gemm_kernel<<<dim3(NB, SPLITS), 256, 0, stream>>>(x, packed, rr, out);
}

// Round 5
// 31.760 us; speedup vs baseline: 1.4389x; 1.1205x over previous
//
#include <hip/hip_runtime.h>
#include <hip/hip_bf16.h>
#include <hip/hip_fp16.h>

typedef __attribute__((ext_vector_type(8))) short short8;   // 8 x bf16 (4 VGPRs)
typedef __attribute__((ext_vector_type(4))) float f32x4;    // MFMA accumulator

#define OUT_F  11008
#define IN_F   4096
#define BN     64
#define SPLITS 4
#define KSTEPS 8              // 128-wide K steps per split (4*8*128 = 4096)
#define NB     (OUT_F / BN)   // 172
#define WBYTES (BN * 256)     // 16384: W tile, 64 rows x 128 bf16 swizzled
#define BUFSZ  (WBYTES + 32 * 256)   // + A tile (32 rows x 128 bf16) = 24576

// ---------- helpers ----------
static __device__ __forceinline__ uint pack2_bf16(float a, float b) {
    __hip_bfloat162 h = __float22bfloat162_rn(make_float2(a, b));
    uint u;
    __builtin_memcpy(&u, &h, 4);
    return u;
}

static __device__ __forceinline__ float bf16_to_f(ushort u) {
    return __uint_as_float(((uint)u) << 16);
}

// dequant 4 weights from one packed int (low byte): w = xmin + q * d
static __device__ __forceinline__ uint2 dq4(int p, float xmin, float dd) {
    float w0 = fmaf((float)(p & 3), dd, xmin);
    float w1 = fmaf((float)((p >> 2) & 3), dd, xmin);
    float w2 = fmaf((float)((p >> 4) & 3), dd, xmin);
    float w3 = fmaf((float)((p >> 6) & 3), dd, xmin);
    return make_uint2(pack2_bf16(w0, w1), pack2_bf16(w2, w3));
}

// decode a prefetched raw range pair under detected format
static __device__ __forceinline__ void rng_decode(uint ru, float2 rf, int fmt,
                                                  float& xmin, float& dd) {
    float xmax;
    if (fmt == 2) {
        xmin = rf.x; xmax = rf.y;
    } else if (fmt == 1) {
        xmin = bf16_to_f((ushort)(ru & 0xffff));
        xmax = bf16_to_f((ushort)(ru >> 16));
    } else {
        __half2 h;
        __builtin_memcpy(&h, &ru, 4);
        xmin = __half2float(h.x); xmax = __half2float(h.y);
    }
    dd = (xmax - xmin) * (1.0f / 3.0f);
}

// ---------- kernel 1: fused detect + dequant + GEMM -> split-K partials ----------
__global__ __launch_bounds__(256, 3)
void gemm_kernel(const float* __restrict__ x,
                 const int* __restrict__ packed,
                 const void* __restrict__ rr,
                 float* __restrict__ part) {
    const int nb   = blockIdx.x;   // 0..171  (64 output cols each)
    const int s    = blockIdx.y;   // 0..3    (K split: 1024 each)
    const int t    = threadIdx.x;  // 0..255
    const int lane = t & 63;
    const int wv   = t >> 6;       // wave id 0..3 -> 16 cols each

    __shared__ __align__(16) char lds[2 * BUFSZ];   // double-buffered W+A tiles
    __shared__ int s_viol[3];
    __shared__ int s_max[3];
    __shared__ int s_fmt;

    // ---- block-local range-dtype detection: 256 contiguous front samples ----
    // g in [1024,1280): f32-view reads bytes [8192,10240) -- in-bounds for every
    // possible actual dtype (smallest buffer = 16-bit pairs = 1.4 MB).
    if (t < 3) { s_viol[t] = 0; s_max[t] = 0; }
    __syncthreads();
    {
        const int g = 1024 + t;
        const uint   ru = ((const uint*)rr)[g];
        const float2 rf = ((const float2*)rr)[g];
        int viol[3]; float mx[3];
        {   // h0: fp16 pairs
            __half2 h; __builtin_memcpy(&h, &ru, 4);
            const float a = __half2float(h.x), c = __half2float(h.y);
            viol[0] = !(fabsf(a) < 1.f && fabsf(c) < 1.f && a <= c);
            mx[0] = fabsf(c);
        }
        {   // h1: bf16 pairs
            const float a = bf16_to_f((ushort)(ru & 0xffff));
            const float c = bf16_to_f((ushort)(ru >> 16));
            viol[1] = !(fabsf(a) < 1.f && fabsf(c) < 1.f && a <= c);
            mx[1] = fabsf(c);
        }
        {   // h2: f32 pairs
            viol[2] = !(fabsf(rf.x) < 1.f && fabsf(rf.y) < 1.f && rf.x <= rf.y);
            mx[2] = fabsf(rf.y);
        }
#pragma unroll
        for (int h = 0; h < 3; ++h) {
            if (viol[h]) atomicOr(&s_viol[h], 1);
            atomicMax(&s_max[h], __float_as_int(mx[h]));   // mx >= 0: int-monotone
        }
    }
    __syncthreads();
    if (t == 0) {
        const float lo = 0.02f;
        int f = 0;
        if      (!s_viol[2] && __int_as_float(s_max[2]) > lo) f = 2;
        else if (!s_viol[1] && __int_as_float(s_max[1]) > lo) f = 1;
        s_fmt = f;
    }
    __syncthreads();
    const int fmt = s_fmt;   // uniform across block

    // ---- addressing ----
    const int i4  = t & 7;   // which int4 within the group's 32 ints
    const int nr0 = t >> 3;  // 0..31 -> W rows {nr0, nr0+32}
    const int n0  = nb * BN + nr0;
    const int n1  = n0 + 32;
    const int kb0 = s * KSTEPS;
    const int* pb0 = packed + n0 * 1024 + i4 * 4;
    const int* pb1 = packed + n1 * 1024 + i4 * 4;
    const uint*   rr_u  = (const uint*)rr;
    const float2* rr_f2 = (const float2*)rr;

    // x stage (writer): thread covers x row t>>3, 16 floats at col (t&7)*16
    const float* xsrc = x + (t >> 3) * IN_F + (t & 7) * 16;
    const uint aswz = (uint)(((t >> 3) & 7) << 4);
    const uint acb  = (uint)((t & 7) * 32);

    // A-frag read offsets (same swizzle family: row&7 invariant under +16)
    const int  ar0  = (lane & 15);
    const uint arsw = (uint)((lane & 7) << 4);

    f32x4 acc0 = {0.f, 0.f, 0.f, 0.f};
    f32x4 acc1 = {0.f, 0.f, 0.f, 0.f};

    // ---- prologue: step-0 operands into "current" registers ----
    int4  p4c0 = *(const int4*)(pb0 + kb0 * 32);
    int4  p4c1 = *(const int4*)(pb1 + kb0 * 32);
    uint  ruc0 = 0, ruc1 = 0;
    float2 rfc0 = {0.f, 0.f}, rfc1 = {0.f, 0.f};
    if (fmt == 2) {
        rfc0 = rr_f2[n0 * 32 + kb0];
        rfc1 = rr_f2[n1 * 32 + kb0];
    } else {
        ruc0 = rr_u[n0 * 32 + kb0];
        ruc1 = rr_u[n1 * 32 + kb0];
    }
    float4 xc0, xc1, xc2, xc3;
    {
        const float* xs = xsrc + (kb0 << 7);
        xc0 = *(const float4*)(xs);
        xc1 = *(const float4*)(xs + 4);
        xc2 = *(const float4*)(xs + 8);
        xc3 = *(const float4*)(xs + 12);
    }

    for (int step = 0; step < KSTEPS; ++step) {
        char* const wt = lds + (step & 1) * BUFSZ;
        char* const at = wt + WBYTES;

        // (a) issue NEXT step's global loads first; they stay in flight across
        //     the (lgkm-only) barrier below -- counted-vmcnt pipeline.
        int4 p4n0, p4n1;
        uint run0 = 0, run1 = 0;
        float2 rfn0 = {0.f, 0.f}, rfn1 = {0.f, 0.f};
        float4 xn0, xn1, xn2, xn3;
        if (step + 1 < KSTEPS) {
            const int kn = kb0 + step + 1;
            p4n0 = *(const int4*)(pb0 + kn * 32);
            p4n1 = *(const int4*)(pb1 + kn * 32);
            if (fmt == 2) {
                rfn0 = rr_f2[n0 * 32 + kn];
                rfn1 = rr_f2[n1 * 32 + kn];
            } else {
                run0 = rr_u[n0 * 32 + kn];
                run1 = rr_u[n1 * 32 + kn];
            }
            const float* xs = xsrc + (kn << 7);
            xn0 = *(const float4*)(xs);
            xn1 = *(const float4*)(xs + 4);
            xn2 = *(const float4*)(xs + 8);
            xn3 = *(const float4*)(xs + 12);
        }

        // (b) stage current x slice -> A tile (bf16, swizzled)
        {
            uint q0 = pack2_bf16(xc0.x, xc0.y), q1 = pack2_bf16(xc0.z, xc0.w);
            uint q2 = pack2_bf16(xc1.x, xc1.y), q3 = pack2_bf16(xc1.z, xc1.w);
            uint q4 = pack2_bf16(xc2.x, xc2.y), q5 = pack2_bf16(xc2.z, xc2.w);
            uint q6 = pack2_bf16(xc3.x, xc3.y), q7 = pack2_bf16(xc3.z, xc3.w);
            char* adst = at + (t >> 3) * 256;
            *(uint4*)(adst + (acb ^ aswz))        = make_uint4(q0, q1, q2, q3);
            *(uint4*)(adst + ((acb + 16) ^ aswz)) = make_uint4(q4, q5, q6, q7);
        }

        // (c) dequant current W registers -> W tile (bf16, swizzled)
        {
            float xmin, dd;
            rng_decode(ruc0, rfc0, fmt, xmin, dd);
            char* dst = wt + nr0 * 256;
            const uint swz = (uint)((nr0 & 7) << 4);
            uint2 q0 = dq4(p4c0.x, xmin, dd);
            uint2 q1 = dq4(p4c0.y, xmin, dd);
            *(uint4*)(dst + (uint)((32 * i4) ^ swz)) = make_uint4(q0.x, q0.y, q1.x, q1.y);
            uint2 q2 = dq4(p4c0.z, xmin, dd);
            uint2 q3 = dq4(p4c0.w, xmin, dd);
            *(uint4*)(dst + (uint)((32 * i4 + 16) ^ swz)) = make_uint4(q2.x, q2.y, q3.x, q3.y);
        }
        {
            float xmin, dd;
            rng_decode(ruc1, rfc1, fmt, xmin, dd);
            const int nr = nr0 + 32;
            char* dst = wt + nr * 256;
            const uint swz = (uint)((nr & 7) << 4);
            uint2 q0 = dq4(p4c1.x, xmin, dd);
            uint2 q1 = dq4(p4c1.y, xmin, dd);
            *(uint4*)(dst + (uint)((32 * i4) ^ swz)) = make_uint4(q0.x, q0.y, q1.x, q1.y);
            uint2 q2 = dq4(p4c1.z, xmin, dd);
            uint2 q3 = dq4(p4c1.w, xmin, dd);
            *(uint4*)(dst + (uint)((32 * i4 + 16) ^ swz)) = make_uint4(q2.x, q2.y, q3.x, q3.y);
        }

        // (d) handoff: drain LDS writes only -- global loads stay in flight.
        asm volatile("s_waitcnt lgkmcnt(0)" ::: "memory");
        __builtin_amdgcn_s_barrier();
        __builtin_amdgcn_sched_barrier(0);

        // (e) A/B fragments from swizzled LDS + MFMA
        {
            const char* asrc0 = at + ar0 * 256;
            const char* asrc1 = at + (ar0 + 16) * 256;
            const int  nrow = (wv << 4) | (lane & 15);
            const char* bsrc = wt + nrow * 256;
            const uint bswz = (uint)((nrow & 7) << 4);
#pragma unroll
            for (int kc = 0; kc < 4; ++kc) {
                const uint cb = (uint)((kc << 6) | ((lane >> 4) << 4));
                short8 av0 = *(const short8*)(asrc0 + (cb ^ arsw));
                short8 av1 = *(const short8*)(asrc1 + (cb ^ arsw));
                short8 bf  = *(const short8*)(bsrc  + (cb ^ bswz));
                acc0 = __builtin_amdgcn_mfma_f32_16x16x32_bf16(av0, bf, acc0, 0, 0, 0);
                acc1 = __builtin_amdgcn_mfma_f32_16x16x32_bf16(av1, bf, acc1, 0, 0, 0);
            }
        }
        // No second barrier: next step writes the OTHER buffer; a wave can only
        // reach the re-write of THIS buffer (step+2) after passing the step+1
        // barrier, which a reader still in (e) hasn't signaled yet.

        // (f) rotate prefetched registers into current slot
        if (step + 1 < KSTEPS) {
            p4c0 = p4n0; p4c1 = p4n1;
            ruc0 = run0; ruc1 = run1;
            rfc0 = rfn0; rfc1 = rfn1;
            xc0 = xn0; xc1 = xn1; xc2 = xn2; xc3 = xn3;
        }
    }

    // ---- epilogue: plain stores of split-K partials ----
    // C/D layout col=lane&15, row=(lane>>4)*4+reg (m89-verified)
    float* pout = part + (size_t)s * (32 * OUT_F);
    const int col = nb * BN + (wv << 4) + (lane & 15);
    const int r0  = (lane >> 4) << 2;
#pragma unroll
    for (int v = 0; v < 4; ++v) {
        pout[(r0 + v) * OUT_F + col]      = acc0[v];
        pout[(16 + r0 + v) * OUT_F + col] = acc1[v];
    }
}

// ---------- kernel 2: out = bias + sum of split-K partials ----------
__global__ __launch_bounds__(256)
void reduce_kernel(const float* __restrict__ part,
                   const float* __restrict__ bias,
                   float* __restrict__ out) {
    const int i = blockIdx.x * 256 + threadIdx.x;   // 0..88063 float4 units
    const int n4 = i % 2752;                        // 11008/4
    const float4* p4 = (const float4*)part;
    float4 a = ((const float4*)bias)[n4];
#pragma unroll
    for (int ss = 0; ss < SPLITS; ++ss) {
        const float4 v = p4[ss * 88064 + i];
        a.x += v.x; a.y += v.y; a.z += v.z; a.w += v.w;
    }
    ((float4*)out)[i] = a;
}

extern "C" void kernel_launch(void* const* d_in, const int* in_sizes, int n_in,
                              void* d_out, int out_size, void* d_ws, size_t ws_size,
                              hipStream_t stream) {
    const float* x      = (const float*)d_in[0];
    const int*   packed = (const int*)d_in[1];
    const void*  rr     = (const void*)d_in[2];
    const float* bias   = (const float*)d_in[3];
    float*       out    = (float*)d_out;
    float*       part   = (float*)d_ws;   // SPLITS * 32 * 11008 f32 = 5.6 MB

    gemm_kernel<<<dim3(NB, SPLITS), 256, 0, stream>>>(x, packed, rr, part);
    reduce_kernel<<<344, 256, 0, stream>>>(part, bias, out);
}